// Round 13
// baseline (1489.851 us; speedup 1.0000x reference)
//
#include <hip/hip_runtime.h>
#include <hip/hip_bf16.h>
#include <cstdint>
#include <cstddef>

#define MROWS 100352   // B*H*W = 32*56*56
#define CDIM  512
#define HDIM  2048

typedef __attribute__((ext_vector_type(4))) float floatx4;
typedef __attribute__((ext_vector_type(4))) int   intx4;
typedef __attribute__((ext_vector_type(8))) int   intx8;

// ---- manual f32 -> e4m3fn (OCP), RNE, FTZ below 2^-6, clamp 448 ---------
// (verified numerically in round 9: end-to-end absmax 0.078 < 0.113)
static __device__ __forceinline__ unsigned int f2fp8(float f) {
  union { float f; unsigned int u; } c; c.f = f;
  const unsigned int u = c.u;
  const unsigned int s = (u >> 24) & 0x80u;
  const unsigned int au = u & 0x7FFFFFFFu;
  if (au < 0x3C800000u) return s;            // |f| < 2^-6 -> +-0 (FTZ)
  if (au > 0x43E00000u) return s | 0x7Eu;    // clamp to 448
  const unsigned int r = au + 0x7FFFFu + ((au >> 20) & 1u);  // RNE at bit 20
  return s | ((r >> 20) - 960u);             // rebias: (127-7)<<3
}

static __device__ __forceinline__ void gload_lds16(const void* g, void* l) {
  __builtin_amdgcn_global_load_lds(
      (const __attribute__((address_space(1))) void*)g,
      (__attribute__((address_space(3))) void*)l, 16, 0, 0);
}

#define BAR()   asm volatile("s_barrier" ::: "memory")
#define LGKM0() asm volatile("s_waitcnt lgkmcnt(0)" ::: "memory")
#define VMC0()  asm volatile("s_waitcnt vmcnt(0)" ::: "memory")

// ---- cast both MLP weight matrices fp32 -> fp8 (x64 scale) --------------
__global__ void cast_weights(const float4* __restrict__ s1, unsigned int* __restrict__ d1,
                             const float4* __restrict__ s2, unsigned int* __restrict__ d2) {
  int t = blockIdx.x * 256 + threadIdx.x;
  const int N4 = (HDIM * CDIM) / 4;
  const float4* s; unsigned int* d; int idx;
  if (t < N4) { s = s1; d = d1; idx = t; }
  else        { s = s2; d = d2; idx = t - N4; }
  float4 f = s[idx];
  d[idx] = f2fp8(f.x * 64.0f) | (f2fp8(f.y * 64.0f) << 8) |
           (f2fp8(f.z * 64.0f) << 16) | (f2fp8(f.w * 64.0f) << 24);
}

// ---- LayerNorm over C=512 + cast to fp8 (x1), one wave per row ----------
__global__ void ln_cast(const float* __restrict__ x, const float* __restrict__ g,
                        const float* __restrict__ b, unsigned int* __restrict__ xn) {
  const int row  = blockIdx.x * 4 + (threadIdx.x >> 6);
  const int lane = threadIdx.x & 63;
  const float4* xr = reinterpret_cast<const float4*>(x + (size_t)row * CDIM);
  const float4 v0 = xr[lane], v1 = xr[lane + 64];
  float s  = v0.x + v0.y + v0.z + v0.w + v1.x + v1.y + v1.z + v1.w;
  float ss = v0.x*v0.x + v0.y*v0.y + v0.z*v0.z + v0.w*v0.w
           + v1.x*v1.x + v1.y*v1.y + v1.z*v1.z + v1.w*v1.w;
#pragma unroll
  for (int o = 1; o < 64; o <<= 1) { s += __shfl_xor(s, o); ss += __shfl_xor(ss, o); }
  const float mean = s * (1.0f / CDIM);
  const float rstd = rsqrtf(ss * (1.0f / CDIM) - mean * mean + 1e-5f);
  const float4* g4 = reinterpret_cast<const float4*>(g);
  const float4* b4 = reinterpret_cast<const float4*>(b);
  const float4 ga = g4[lane], gb = g4[lane + 64];
  const float4 ba = b4[lane], bb = b4[lane + 64];
  const unsigned int p0 =
      f2fp8((v0.x - mean) * rstd * ga.x + ba.x)
    | (f2fp8((v0.y - mean) * rstd * ga.y + ba.y) << 8)
    | (f2fp8((v0.z - mean) * rstd * ga.z + ba.z) << 16)
    | (f2fp8((v0.w - mean) * rstd * ga.w + ba.w) << 24);
  const unsigned int p1 =
      f2fp8((v1.x - mean) * rstd * gb.x + bb.x)
    | (f2fp8((v1.y - mean) * rstd * gb.y + bb.y) << 8)
    | (f2fp8((v1.z - mean) * rstd * gb.z + bb.z) << 16)
    | (f2fp8((v1.w - mean) * rstd * gb.w + bb.w) << 24);
  unsigned int* orow = xn + (size_t)row * (CDIM / 4);
  orow[lane]      = p0;
  orow[lane + 64] = p1;
}

// ---- MX-fp8 GEMM: C = A(MxK) * Bw(NxK)^T, 128x128 tile, BK=128 ----------
// mfma_scale_f32_16x16x128_f8f6f4 with UNIFORM scales (0x7F7F7F7F = 2^0 in
// every E8M0 byte -> scale-operand lane layout is irrelevant). 2x bf16 MFMA
// rate, half the LDS bytes per FLOP. 256 threads = 4 waves (2x2, 64x64).
// LDS 32KB single buffer (R11-verified overwrite schedule), ~3 blocks/CU.
// Per K-iter (BK=128): {16 ds_read_b128 (2 per 32B frag); LGKM0+BAR
// (buffer dead block-wide); STG(kt+1) overwrite (8 gload_lds); 16 MFMA
// (covers flight); VMC0+BAR}.
// Swizzle (R6-verified 0-conflict geometry, byte-identical: 8x16B chunks
// per 128B row): LDS slot s of row r holds src chunk s^(r&7); src chunk =
// (tid^(tid>>3))&7; read slot = kslot^(row&7). Bank count: 8 words/bank =
// HW minimum.
// Swapped-operand MFMA: D[m=lane&15][n=(lane>>4)*4+reg] (C/D layout is
// dtype-independent) -> lane holds 4 consecutive N cols.
// Scales: A carries x1 (gemm1) / x8 (G), B carries x64 -> SCI divides out.
// EPI=1: out = fp8(8*gelu_sigmoid(acc/64+bias)); EPI=2: f32 acc/512+bias+resid.
template<int KDIM, int NDIM, int EPI>
__global__ __launch_bounds__(256, 3) void gemm_mx(
    const unsigned char* __restrict__ A, const unsigned char* __restrict__ Bw,
    const float* __restrict__ bias, const float* __restrict__ resid,
    void* __restrict__ Cout) {
  constexpr int nt = KDIM / 128;
  __shared__ __align__(16) unsigned char smA[128 * 128];   // 16KB
  __shared__ __align__(16) unsigned char smB[128 * 128];   // 16KB

  const int tid  = threadIdx.x;
  const int lane = tid & 63, w = tid >> 6;
  const int swr = w >> 1, swc = w & 1;             // wave 2x2 grid, 64x64
  const int frow  = lane & 15;
  const int kslot = (lane >> 4) * 2;               // 16B-slot base of 32B k-group

  // XCD-aware bijective swizzle (grid % 8 == 0); consecutive lids share
  // the A m-panel -> L2 reuse within an XCD.
  constexpr int GX = NDIM / 128;
  const int nwg = gridDim.x;
  const int lid = ((int)blockIdx.x & 7) * (nwg >> 3) + ((int)blockIdx.x >> 3);
  const int m0 = (lid / GX) * 128, n0 = (lid % GX) * 128;

  // staging: thread -> row tid>>3 of each 32-row group, dest 16B slot tid&7,
  // source chunk (tid&7)^((tid>>3)&7)  [involution with the read XOR]
  const int srow = tid >> 3;                       // 0..31
  const int scb  = ((tid ^ (tid >> 3)) & 7) * 16;
  const unsigned char* gA = A  + (size_t)(m0 + srow) * KDIM + scb;
  const unsigned char* gB = Bw + (size_t)(n0 + srow) * KDIM + scb;

  auto STG = [&](int kt) {
    const unsigned char* sa = gA + (size_t)kt * 128;
    const unsigned char* sb = gB + (size_t)kt * 128;
#pragma unroll
    for (int j = 0; j < 4; ++j) {                  // rows j*32 .. j*32+31
      gload_lds16(sa + (size_t)j * 32 * KDIM, &smA[j * 4096 + tid * 16]);
      gload_lds16(sb + (size_t)j * 32 * KDIM, &smB[j * 4096 + tid * 16]);
    }
  };

  floatx4 acc[4][4] = {};   // [mi][nj]

  STG(0);
  VMC0();
  BAR();

  for (int kt = 0; kt < nt; ++kt) {
    intx8 af[4], bf[4];
#pragma unroll
    for (int mi = 0; mi < 4; ++mi) {
      const int row = swr * 64 + mi * 16 + frow;
      const int rx  = row & 7;
      const intx4 lo = *reinterpret_cast<const intx4*>(
          &smA[row * 128 + ((kslot ^ rx) * 16)]);
      const intx4 hi = *reinterpret_cast<const intx4*>(
          &smA[row * 128 + (((kslot + 1) ^ rx) * 16)]);
      af[mi] = __builtin_shufflevector(lo, hi, 0, 1, 2, 3, 4, 5, 6, 7);
    }
#pragma unroll
    for (int nj = 0; nj < 4; ++nj) {
      const int row = swc * 64 + nj * 16 + frow;
      const int rx  = row & 7;
      const intx4 lo = *reinterpret_cast<const intx4*>(
          &smB[row * 128 + ((kslot ^ rx) * 16)]);
      const intx4 hi = *reinterpret_cast<const intx4*>(
          &smB[row * 128 + (((kslot + 1) ^ rx) * 16)]);
      bf[nj] = __builtin_shufflevector(lo, hi, 0, 1, 2, 3, 4, 5, 6, 7);
    }

    LGKM0();                       // own frags in regs
    BAR();                         // block-wide: buffer fully read -> dead
    if (kt + 1 < nt) STG(kt + 1);  // overwrite; flight covered by MFMA

    __builtin_amdgcn_s_setprio(1);
#pragma unroll
    for (int mi = 0; mi < 4; ++mi)
#pragma unroll
      for (int nj = 0; nj < 4; ++nj)   // swapped operands: N -> reg dim
        acc[mi][nj] = __builtin_amdgcn_mfma_scale_f32_16x16x128_f8f6f4(
            bf[nj], af[mi], acc[mi][nj],
            0, 0,                       // cbsz, blgp: fp8 e4m3 / fp8 e4m3
            0, 0x7F7F7F7F,              // scale A: opsel 0, all bytes 2^0
            0, 0x7F7F7F7F);             // scale B: opsel 0, all bytes 2^0
    __builtin_amdgcn_s_setprio(0);

    if (kt + 1 < nt) { VMC0(); BAR(); }  // next tile landed + published
  }

  // epilogue (swapped layout): gm = ...+lane&15, gn = ...+(lane>>4)*4 + r
  const int em = lane & 15;
  const int en = (lane >> 4) << 2;
  constexpr float SCI = (EPI == 1) ? (1.0f / 64.0f) : (1.0f / 512.0f);

  float4 bj[4];
#pragma unroll
  for (int nj = 0; nj < 4; ++nj)
    bj[nj] = *reinterpret_cast<const float4*>(&bias[n0 + swc * 64 + nj * 16 + en]);

#pragma unroll
  for (int mi = 0; mi < 4; ++mi) {
    const int gm = m0 + swr * 64 + mi * 16 + em;
    const size_t rowoff = (size_t)gm * NDIM + n0 + swc * 64 + en;
#pragma unroll
    for (int nj = 0; nj < 4; ++nj) {
      const float4 bb = bj[nj];
      const floatx4 av = acc[mi][nj];
      float v0 = av[0] * SCI + bb.x, v1 = av[1] * SCI + bb.y;
      float v2 = av[2] * SCI + bb.z, v3 = av[3] * SCI + bb.w;
      const size_t off = rowoff + nj * 16;
      if (EPI == 1) {
        // gelu ~= v * sigmoid(1.702 v); store fp8(8 * gelu)
        v0 *= 8.0f * __builtin_amdgcn_rcpf(1.0f + __expf(-1.702f * v0));
        v1 *= 8.0f * __builtin_amdgcn_rcpf(1.0f + __expf(-1.702f * v1));
        v2 *= 8.0f * __builtin_amdgcn_rcpf(1.0f + __expf(-1.702f * v2));
        v3 *= 8.0f * __builtin_amdgcn_rcpf(1.0f + __expf(-1.702f * v3));
        *reinterpret_cast<unsigned int*>((unsigned char*)Cout + off) =
            f2fp8(v0) | (f2fp8(v1) << 8) | (f2fp8(v2) << 16) | (f2fp8(v3) << 24);
      } else {
        const float4 r4 = *reinterpret_cast<const float4*>(resid + off);
        float4 o = make_float4(v0 + r4.x, v1 + r4.y, v2 + r4.z, v3 + r4.w);
        *reinterpret_cast<float4*>((float*)Cout + off) = o;
      }
    }
  }
}

extern "C" void kernel_launch(void* const* d_in, const int* in_sizes, int n_in,
                              void* d_out, int out_size, void* d_ws, size_t ws_size,
                              hipStream_t stream) {
  // input order: x wqkv bqkv wo bo g1 b1 g2 b2 w_mlp1 b_mlp1 w_mlp2 b_mlp2
  const float* x   = (const float*)d_in[0];
  const float* g2  = (const float*)d_in[7];
  const float* b2  = (const float*)d_in[8];
  const float* w1  = (const float*)d_in[9];
  const float* b1  = (const float*)d_in[10];
  const float* w2  = (const float*)d_in[11];
  const float* b2m = (const float*)d_in[12];
  float* out = (float*)d_out;

  // Output is exactly x + MLP(LN(x,g2,b2)) — the attention branch of the
  // reference is discarded (xr == x after the two opposite rolls).

  // workspace (fp8): w1b (1MB, x64) | w2b (1MB, x64) | G (205MB, x8)
  unsigned char* w1b = (unsigned char*)d_ws;
  unsigned char* w2b = w1b + (size_t)HDIM * CDIM;
  unsigned char* G   = w2b + (size_t)HDIM * CDIM;
  // LN output (fp8, 51MB) parked in d_out; consumed by GEMM1 before GEMM2
  // overwrites d_out with the final result (stream-ordered).
  unsigned char* xn = (unsigned char*)d_out;

  cast_weights<<<2048, 256, 0, stream>>>(
      (const float4*)w1, (unsigned int*)w1b, (const float4*)w2, (unsigned int*)w2b);
  ln_cast<<<MROWS / 4, 256, 0, stream>>>(x, g2, b2, (unsigned int*)xn);

  // gemm1: (M x 512)*(2048 x 512)^T -> gelu -> fp8 G ; grid 12544 (%8==0)
  gemm_mx<CDIM, HDIM, 1>
      <<<dim3((MROWS / 128) * (HDIM / 128)), 256, 0, stream>>>(
          xn, w1b, b1, nullptr, (void*)G);

  // gemm2: (M x 2048)*(512 x 2048)^T + bias + x -> f32 out ; grid 3136 (%8==0)
  gemm_mx<HDIM, CDIM, 2>
      <<<dim3((MROWS / 128) * (CDIM / 128)), 256, 0, stream>>>(
          G, w2b, b2m, x, (void*)out);
}

// Round 14
// 802.251 us; speedup vs baseline: 1.8571x; 1.8571x over previous
//
#include <hip/hip_runtime.h>
#include <hip/hip_bf16.h>
#include <cstdint>
#include <cstddef>

#define MROWS 100352   // B*H*W = 32*56*56
#define CDIM  512
#define HDIM  2048

typedef __attribute__((ext_vector_type(8))) short   short8;
typedef __attribute__((ext_vector_type(8))) __bf16  bf16x8;
typedef __attribute__((ext_vector_type(4))) __bf16  bf16x4;
typedef __attribute__((ext_vector_type(4))) float   floatx4;

static __device__ __forceinline__ unsigned short f2bf(float f) {
  union { float f; unsigned int u; } c; c.f = f;
  unsigned int u = c.u;
  return (unsigned short)((u + 0x7FFFu + ((u >> 16) & 1u)) >> 16);  // RNE
}

static __device__ __forceinline__ void gload_lds16(const void* g, void* l) {
  __builtin_amdgcn_global_load_lds(
      (const __attribute__((address_space(1))) void*)g,
      (__attribute__((address_space(3))) void*)l, 16, 0, 0);
}

#define BAR()   asm volatile("s_barrier" ::: "memory")
#define LGKM0() asm volatile("s_waitcnt lgkmcnt(0)" ::: "memory")

template<int N> static __device__ __forceinline__ void vm_wait() {
  if constexpr (N == 0)      asm volatile("s_waitcnt vmcnt(0)" ::: "memory");
  else if constexpr (N == 3) asm volatile("s_waitcnt vmcnt(3)" ::: "memory");
  else if constexpr (N == 4) asm volatile("s_waitcnt vmcnt(4)" ::: "memory");
  else if constexpr (N == 6) asm volatile("s_waitcnt vmcnt(6)" ::: "memory");
}

// ---- cast both MLP weight matrices fp32 -> bf16 -------------------------
__global__ void cast_weights(const float4* __restrict__ s1, unsigned short* __restrict__ d1,
                             const float4* __restrict__ s2, unsigned short* __restrict__ d2) {
  int t = blockIdx.x * 256 + threadIdx.x;
  const int N4 = (HDIM * CDIM) / 4;
  const float4* s; unsigned short* d; int idx;
  if (t < N4) { s = s1; d = d1; idx = t; }
  else        { s = s2; d = d2; idx = t - N4; }
  float4 f = s[idx];
  ushort4 u = make_ushort4(f2bf(f.x), f2bf(f.y), f2bf(f.z), f2bf(f.w));
  *reinterpret_cast<ushort4*>(d + (size_t)idx * 4) = u;
}

// ---- LayerNorm over C=512 + cast to bf16, one wave per row --------------
__global__ void ln_cast(const float* __restrict__ x, const float* __restrict__ g,
                        const float* __restrict__ b, unsigned short* __restrict__ xn) {
  const int row  = blockIdx.x * 4 + (threadIdx.x >> 6);
  const int lane = threadIdx.x & 63;
  const float4* xr = reinterpret_cast<const float4*>(x + (size_t)row * CDIM);
  const float4 v0 = xr[lane], v1 = xr[lane + 64];
  float s  = v0.x + v0.y + v0.z + v0.w + v1.x + v1.y + v1.z + v1.w;
  float ss = v0.x*v0.x + v0.y*v0.y + v0.z*v0.z + v0.w*v0.w
           + v1.x*v1.x + v1.y*v1.y + v1.z*v1.z + v1.w*v1.w;
#pragma unroll
  for (int o = 1; o < 64; o <<= 1) { s += __shfl_xor(s, o); ss += __shfl_xor(ss, o); }
  const float mean = s * (1.0f / CDIM);
  const float rstd = rsqrtf(ss * (1.0f / CDIM) - mean * mean + 1e-5f);
  const float4* g4 = reinterpret_cast<const float4*>(g);
  const float4* b4 = reinterpret_cast<const float4*>(b);
  const float4 ga = g4[lane], gb = g4[lane + 64];
  const float4 ba = b4[lane], bb = b4[lane + 64];
  ushort4 o0 = make_ushort4(
      f2bf((v0.x - mean) * rstd * ga.x + ba.x),
      f2bf((v0.y - mean) * rstd * ga.y + ba.y),
      f2bf((v0.z - mean) * rstd * ga.z + ba.z),
      f2bf((v0.w - mean) * rstd * ga.w + ba.w));
  ushort4 o1 = make_ushort4(
      f2bf((v1.x - mean) * rstd * gb.x + bb.x),
      f2bf((v1.y - mean) * rstd * gb.y + bb.y),
      f2bf((v1.z - mean) * rstd * gb.z + bb.z),
      f2bf((v1.w - mean) * rstd * gb.w + bb.w));
  unsigned short* orow = xn + (size_t)row * CDIM;
  *reinterpret_cast<ushort4*>(orow + lane * 4)        = o0;
  *reinterpret_cast<ushort4*>(orow + (lane + 64) * 4) = o1;
}

// ---- BM x BN quadrant-scheduled GEMM (round-6 verified structure) -------
// C = A(MxK) * Bw(NxK)^T. 512 threads = 8 waves (2M x 4N), BK=64.
// LDS: A 2dbuf x 2half x (BM/2 x 64), B same with BN/2. Per K-tile, 4
// phases (one C-quadrant each) interleave ds_reads, half-tile prefetch
// stages, MFMA clusters (setprio), with counted vmcnt — never 0 mid-loop.
// Balanced XOR swizzle: LDS 16B-slot s of row r holds src chunk s^(r&7)
// (pre-swizzled global source + same XOR on ds_read; verified 0-conflict).
// Swapped-operand mfma_f32_16x16x32_bf16: D[m=lane&15][n=(lane>>4)*4+reg]
// -> lane holds 4 consecutive N cols; vectorized epilogue.
// EPI=1: out = bf16(gelu_sigmoid(acc+bias)); EPI=2: f32 acc+bias+resid.
template<int KDIM, int NDIM, int BM, int BN, int EPI>
__global__ __launch_bounds__(512, 1) void gemm_q(
    const unsigned short* __restrict__ A, const unsigned short* __restrict__ Bw,
    const float* __restrict__ bias, const float* __restrict__ resid,
    void* __restrict__ Cout) {
  constexpr int HA = BM / 2, HB = BN / 2;       // half-tile rows
  constexpr int LA = HA / 64, LB = HB / 64;     // gloads per half-stage
  constexpr int MI = HA / 32, NJ = HB / 64;     // per-wave 16-frag counts
  constexpr int nt = KDIM / 64;

  __shared__ __align__(16) unsigned short smA[2][2][HA * 64];
  __shared__ __align__(16) unsigned short smB[2][2][HB * 64];

  const int tid  = threadIdx.x;
  const int lane = tid & 63, w = tid >> 6;
  const int swr = w >> 2, swc = w & 3;           // wave 2x4 grid
  const int frow = tid & 15, fk = ((tid & 63) >> 4) * 8;

  // XCD-aware bijective swizzle (grid % 8 == 0 for both launches)
  constexpr int GX = NDIM / BN;
  const int nwg = gridDim.x;
  const int lid = ((int)blockIdx.x & 7) * (nwg >> 3) + ((int)blockIdx.x >> 3);
  const int m0 = (lid / GX) * BM, n0 = (lid % GX) * BN;

  const size_t ldb = (size_t)KDIM * 2;
  const int srow = tid >> 3;
  const int scb  = ((tid ^ (tid >> 3)) & 7) * 16;
  const char* gA = (const char*)A  + (size_t)(m0 + srow) * ldb + scb;
  const char* gB = (const char*)Bw + (size_t)(n0 + srow) * ldb + scb;

  auto STGA = [&](int tile, int half) {
    const char* s = gA + (size_t)half * HA * ldb + (size_t)tile * 128;
#pragma unroll
    for (int j = 0; j < LA; ++j)
      gload_lds16(s + (size_t)j * 64 * ldb,
                  &smA[tile & 1][half][j * 4096 + w * 512]);
  };
  auto STGB = [&](int tile, int half) {
    const char* s = gB + (size_t)half * HB * ldb + (size_t)tile * 128;
#pragma unroll
    for (int j = 0; j < LB; ++j)
      gload_lds16(s + (size_t)j * 64 * ldb,
                  &smB[tile & 1][half][j * 4096 + w * 512]);
  };
  auto LDA = [&](bf16x8* a, int db, int qm) {
#pragma unroll
    for (int mi = 0; mi < MI; ++mi)
#pragma unroll
      for (int kk = 0; kk < 2; ++kk) {
        const int row = swr * (HA / 2) + mi * 16 + frow;
        const int col = kk * 32 + fk;
        const int sidx = row * 64 + (col ^ ((row & 7) << 3));
        a[mi * 2 + kk] = __builtin_bit_cast(bf16x8,
            *reinterpret_cast<const short8*>(&smA[db][qm][sidx]));
      }
  };
  auto LDBf = [&](bf16x8* b, int db, int qn) {
#pragma unroll
    for (int nj = 0; nj < NJ; ++nj)
#pragma unroll
      for (int kk = 0; kk < 2; ++kk) {
        const int row = swc * (HB / 4) + nj * 16 + frow;
        const int col = kk * 32 + fk;
        const int sidx = row * 64 + (col ^ ((row & 7) << 3));
        b[nj * 2 + kk] = __builtin_bit_cast(bf16x8,
            *reinterpret_cast<const short8*>(&smB[db][qn][sidx]));
      }
  };

  floatx4 acc[2][2][MI][NJ] = {};
  auto MM = [&](floatx4 (&a2)[MI][NJ], const bf16x8* a, const bf16x8* b) {
    __builtin_amdgcn_s_setprio(1);
#pragma unroll
    for (int mi = 0; mi < MI; ++mi)
#pragma unroll
      for (int nj = 0; nj < NJ; ++nj)
#pragma unroll
        for (int kk = 0; kk < 2; ++kk)   // swapped operands: N -> reg dim
          a2[mi][nj] = __builtin_amdgcn_mfma_f32_16x16x32_bf16(
              b[nj * 2 + kk], a[mi * 2 + kk], a2[mi][nj], 0, 0, 0);
    __builtin_amdgcn_s_setprio(0);
  };

  // prologue: tile0 all 4 halves + tile1 A0,B0; wait tile0, keep t1 in flight
  STGA(0, 0); STGB(0, 0);
  STGA(0, 1); STGB(0, 1);
  STGA(1, 0); STGB(1, 0);
  vm_wait<LA + LB>();
  BAR();

  for (int t2 = 0; t2 < nt; ++t2) {
    const int db = t2 & 1;
    bf16x8 a[MI * 2], b0[NJ * 2], b1[NJ * 2];

    // ph1: quadrant (0,0) — reads A0,B0; stage (t+1).A1
    LDA(a, db, 0); LDBf(b0, db, 0);
    if (t2 + 1 < nt) STGA(t2 + 1, 1);
    BAR(); LGKM0();
    MM(acc[0][0], a, b0);
    BAR();

    // ph2: (0,1) — reads B1 (A regs reused); stage (t+1).B1
    LDBf(b1, db, 1);
    if (t2 + 1 < nt) STGB(t2 + 1, 1);
    BAR(); LGKM0();
    MM(acc[0][1], a, b1);
    BAR();

    // ph3: (1,0) — reads A1 (B0 regs reused); stage (t+2).A0
    LDA(a, db, 1);
    if (t2 + 2 < nt) STGA(t2 + 2, 0);
    BAR(); LGKM0();
    MM(acc[1][0], a, b0);
    BAR();

    // ph4: (1,1) — no new reads; stage (t+2).B0
    if (t2 + 2 < nt) STGB(t2 + 2, 0);
    BAR(); LGKM0();
    MM(acc[1][1], a, b1);
    // counted wait: (t+1) halves landed, (t+2) stays in flight
    if (t2 < nt - 2)       { vm_wait<LA + LB>(); }
    else if (t2 == nt - 2) { vm_wait<0>(); }
    BAR();
  }

  // epilogue (swapped layout): gm = ...+lane&15, gn = ...+(lane>>4)*4 + r
  const int em = lane & 15;
  const int en = (lane >> 4) << 2;

  float4 bj[2 * NJ];
#pragma unroll
  for (int qn = 0; qn < 2; ++qn)
#pragma unroll
    for (int nj = 0; nj < NJ; ++nj)
      bj[qn * NJ + nj] = *reinterpret_cast<const float4*>(
          &bias[n0 + qn * HB + swc * (HB / 4) + nj * 16 + en]);

#pragma unroll
  for (int qm = 0; qm < 2; ++qm)
#pragma unroll
    for (int mi = 0; mi < MI; ++mi) {
      const int gm = m0 + qm * HA + swr * (HA / 2) + mi * 16 + em;
      const size_t rowoff = (size_t)gm * NDIM + n0 + swc * (HB / 4) + en;
#pragma unroll
      for (int qn = 0; qn < 2; ++qn)
#pragma unroll
        for (int nj = 0; nj < NJ; ++nj) {
          const float4 bb = bj[qn * NJ + nj];
          const floatx4 av = acc[qm][qn][mi][nj];
          float v0 = av[0] + bb.x, v1 = av[1] + bb.y;
          float v2 = av[2] + bb.z, v3 = av[3] + bb.w;
          const size_t off = rowoff + qn * HB + nj * 16;
          if (EPI == 1) {
            // gelu ~= v * sigmoid(1.702 v)  (max dev ~0.01, threshold 0.113)
            v0 *= __builtin_amdgcn_rcpf(1.0f + __expf(-1.702f * v0));
            v1 *= __builtin_amdgcn_rcpf(1.0f + __expf(-1.702f * v1));
            v2 *= __builtin_amdgcn_rcpf(1.0f + __expf(-1.702f * v2));
            v3 *= __builtin_amdgcn_rcpf(1.0f + __expf(-1.702f * v3));
            bf16x4 o = { (__bf16)v0, (__bf16)v1, (__bf16)v2, (__bf16)v3 };
            *reinterpret_cast<bf16x4*>((unsigned short*)Cout + off) = o;
          } else {
            const float4 r4 = *reinterpret_cast<const float4*>(resid + off);
            float4 o = make_float4(v0 + r4.x, v1 + r4.y, v2 + r4.z, v3 + r4.w);
            *reinterpret_cast<float4*>((float*)Cout + off) = o;
          }
        }
    }
}

extern "C" void kernel_launch(void* const* d_in, const int* in_sizes, int n_in,
                              void* d_out, int out_size, void* d_ws, size_t ws_size,
                              hipStream_t stream) {
  // input order: x wqkv bqkv wo bo g1 b1 g2 b2 w_mlp1 b_mlp1 w_mlp2 b_mlp2
  const float* x   = (const float*)d_in[0];
  const float* g2  = (const float*)d_in[7];
  const float* b2  = (const float*)d_in[8];
  const float* w1  = (const float*)d_in[9];
  const float* b1  = (const float*)d_in[10];
  const float* w2  = (const float*)d_in[11];
  const float* b2m = (const float*)d_in[12];
  float* out = (float*)d_out;

  // Output is exactly x + MLP(LN(x,g2,b2)) — the attention branch of the
  // reference is discarded (xr == x after the two opposite rolls).

  // workspace: w1b (2MB bf16) | w2b (2MB bf16) | G (411MB bf16)
  unsigned short* w1b = (unsigned short*)d_ws;
  unsigned short* w2b = w1b + (size_t)HDIM * CDIM;
  unsigned short* G   = w2b + (size_t)HDIM * CDIM;
  // LN output (bf16, 103MB) parked in d_out; consumed by GEMM1 before GEMM2
  // overwrites d_out with the final result (stream-ordered).
  unsigned short* xn = (unsigned short*)d_out;

  cast_weights<<<2048, 256, 0, stream>>>((const float4*)w1, w1b, (const float4*)w2, w2b);
  ln_cast<<<MROWS / 4, 256, 0, stream>>>(x, g2, b2, xn);

  // gemm1: 256x256 (round-6 verified geometry); grid 392*8 = 3136 (%8==0)
  gemm_q<CDIM, HDIM, 256, 256, 1>
      <<<dim3((MROWS / 256) * (HDIM / 256)), 512, 0, stream>>>(
          xn, w1b, b1, nullptr, (void*)G);

  // gemm2: 256x128 -> grid 392*4 = 1568 (%8==0, 87.5% tail util; was 784)
  gemm_q<HDIM, CDIM, 256, 128, 2>
      <<<dim3((MROWS / 256) * (CDIM / 128)), 512, 0, stream>>>(
          G, w2b, b2m, x, (void*)out);
}